// Round 1
// baseline (624.809 us; speedup 1.0000x reference)
//
#include <hip/hip_runtime.h>

typedef unsigned short ushort_t;
typedef short short8 __attribute__((ext_vector_type(8)));
typedef unsigned short ushort8 __attribute__((ext_vector_type(8)));
typedef unsigned short ushortx4 __attribute__((ext_vector_type(4)));
typedef float fx4 __attribute__((ext_vector_type(4)));
typedef int ix4 __attribute__((ext_vector_type(4)));

#define MFMA(a, b, c) __builtin_amdgcn_mfma_f32_16x16x32_bf16((a), (b), (c), 0, 0, 0)

__device__ __forceinline__ ushort_t f2bf(float f) {
  union { float f; unsigned u; } c; c.f = f;
  unsigned u = (c.u + 0x7FFFu + ((c.u >> 16) & 1u)) >> 16;
  return (ushort_t)u;
}
__device__ __forceinline__ float bf2f(ushort_t h) {
  union { unsigned u; float f; } c; c.u = ((unsigned)h) << 16;
  return c.f;
}

// ---------------- f32 -> bf16 elementwise convert (for weights) ----------------
__global__ __launch_bounds__(256) void cvt_kernel(const float* __restrict__ src,
                                                  ushort_t* __restrict__ dst, int n4) {
  int i = blockIdx.x * 256 + threadIdx.x;
  if (i < n4) {
    fx4 v = *(const fx4*)&src[(size_t)i * 4];
    ushortx4 o;
    o[0] = f2bf(v[0]); o[1] = f2bf(v[1]); o[2] = f2bf(v[2]); o[3] = f2bf(v[3]);
    *(ushortx4*)&dst[(size_t)i * 4] = o;
  }
}

// ---------------- LayerNorm: x (f32, row=1024) -> xn (bf16) ----------------
__global__ __launch_bounds__(256) void ln_kernel(const float* __restrict__ x,
                                                 const float* __restrict__ sc,
                                                 const float* __restrict__ bi,
                                                 ushort_t* __restrict__ xn) {
  __shared__ float red[8];
  int row = blockIdx.x, tid = threadIdx.x;
  const float* xr = x + (size_t)row * 1024;
  fx4 v = *(const fx4*)&xr[tid * 4];
  float s = v[0] + v[1] + v[2] + v[3];
  float s2 = v[0] * v[0] + v[1] * v[1] + v[2] * v[2] + v[3] * v[3];
#pragma unroll
  for (int m = 32; m >= 1; m >>= 1) {
    s += __shfl_xor(s, m);
    s2 += __shfl_xor(s2, m);
  }
  int wave = tid >> 6;
  if ((tid & 63) == 0) { red[wave * 2] = s; red[wave * 2 + 1] = s2; }
  __syncthreads();
  s = red[0] + red[2] + red[4] + red[6];
  s2 = red[1] + red[3] + red[5] + red[7];
  float mu = s * (1.f / 1024.f);
  float var = s2 * (1.f / 1024.f) - mu * mu;
  float rs = rsqrtf(var + 1e-5f);
  fx4 scv = *(const fx4*)&sc[tid * 4];
  fx4 biv = *(const fx4*)&bi[tid * 4];
  ushortx4 o;
#pragma unroll
  for (int j = 0; j < 4; ++j) o[j] = f2bf((v[j] - mu) * rs * scv[j] + biv[j]);
  *(ushortx4*)&xn[(size_t)row * 1024 + tid * 4] = o;
}

// ---------------- GEMM: C[M][N] = A[M][K] @ B[N][K]^T + bias ----------------
// A,B bf16; C bf16 or f32. 128x128 tile, BK=32, 4 waves (2x2 of 64x64).
template <int F32OUT>
__global__ __launch_bounds__(256) void gemm_bt(const ushort_t* __restrict__ A,
                                               const ushort_t* __restrict__ B,
                                               const float* __restrict__ bias, void* C,
                                               int M, int N, int K) {
  __shared__ ushort_t lA[128][40];
  __shared__ ushort_t lB[128][40];
  int bm = blockIdx.y * 128, bn = blockIdx.x * 128;
  int tid = threadIdx.x;
  int wave = tid >> 6, lane = tid & 63;
  int wm = (wave >> 1) * 64, wn = (wave & 1) * 64;
  int l15 = lane & 15, lg = lane >> 4;
  fx4 acc[4][4] = {};
  for (int k0 = 0; k0 < K; k0 += 32) {
    __syncthreads();
#pragma unroll
    for (int it = 0; it < 2; ++it) {
      int idx = tid + it * 256;  // 0..511
      int r = idx >> 2, c8 = (idx & 3) * 8;
      *(ushort8*)&lA[r][c8] = *(const ushort8*)&A[(size_t)(bm + r) * K + k0 + c8];
      *(ushort8*)&lB[r][c8] = *(const ushort8*)&B[(size_t)(bn + r) * K + k0 + c8];
    }
    __syncthreads();
    short8 af[4], bf[4];
#pragma unroll
    for (int i = 0; i < 4; ++i) af[i] = *(const short8*)&lA[wm + i * 16 + l15][lg * 8];
#pragma unroll
    for (int i = 0; i < 4; ++i) bf[i] = *(const short8*)&lB[wn + i * 16 + l15][lg * 8];
#pragma unroll
    for (int i = 0; i < 4; ++i)
#pragma unroll
      for (int j = 0; j < 4; ++j) acc[i][j] = MFMA(af[i], bf[j], acc[i][j]);
  }
#pragma unroll
  for (int j = 0; j < 4; ++j) {
    int n = bn + wn + j * 16 + l15;
    float bv = bias[n];
#pragma unroll
    for (int i = 0; i < 4; ++i) {
      int mr = bm + wm + i * 16 + lg * 4;
#pragma unroll
      for (int r = 0; r < 4; ++r) {
        float val = acc[i][j][r] + bv;
        if (F32OUT)
          ((float*)C)[(size_t)(mr + r) * N + n] = val;
        else
          ((ushort_t*)C)[(size_t)(mr + r) * N + n] = f2bf(val);
      }
    }
  }
}

// ---------------- B_all[bh][t][s] = sum_d q[b,t,h*64+d] * pos_k[t,s,d] ----------------
// one block per t; M=128 (bh), N=1024 (s, 256/wave), K=64
__global__ __launch_bounds__(256) void ball_kernel(const ushort_t* __restrict__ q,
                                                   const float* __restrict__ pos_k,
                                                   ushort_t* __restrict__ B_all) {
  __shared__ ushort_t lq[128][72];
  int t = blockIdx.x, tid = threadIdx.x;
#pragma unroll
  for (int it = 0; it < 4; ++it) {
    int idx = tid + it * 256;  // 0..1023
    int bh = idx >> 3, c8 = (idx & 7) * 8;
    int b = bh >> 4, h = bh & 15;
    *(ushort8*)&lq[bh][c8] = *(const ushort8*)&q[((size_t)(b * 1024 + t)) * 1024 + h * 64 + c8];
  }
  __syncthreads();
  int wave = tid >> 6, lane = tid & 63, l15 = lane & 15, lg = lane >> 4;
  short8 aq[8][2];
#pragma unroll
  for (int mf = 0; mf < 8; ++mf)
#pragma unroll
    for (int ks = 0; ks < 2; ++ks)
      aq[mf][ks] = *(const short8*)&lq[mf * 16 + l15][ks * 32 + lg * 8];
  const float* pk = pos_k + (size_t)t * 1024 * 64;
  for (int sf = 0; sf < 16; ++sf) {
    int s = wave * 256 + sf * 16 + l15;
    short8 bfr[2];
#pragma unroll
    for (int ks = 0; ks < 2; ++ks) {
      const float* p = pk + (size_t)s * 64 + ks * 32 + lg * 8;
      fx4 p0 = *(const fx4*)p;
      fx4 p1 = *(const fx4*)(p + 4);
      short8 r;
#pragma unroll
      for (int j = 0; j < 4; ++j) { r[j] = (short)f2bf(p0[j]); r[j + 4] = (short)f2bf(p1[j]); }
      bfr[ks] = r;
    }
    fx4 acc[8] = {};
#pragma unroll
    for (int mf = 0; mf < 8; ++mf) {
      acc[mf] = MFMA(aq[mf][0], bfr[0], acc[mf]);
      acc[mf] = MFMA(aq[mf][1], bfr[1], acc[mf]);
    }
#pragma unroll
    for (int mf = 0; mf < 8; ++mf)
#pragma unroll
      for (int r = 0; r < 4; ++r) {
        int bh = mf * 16 + lg * 4 + r;
        B_all[((size_t)bh * 1024 + t) * 1024 + s] = f2bf(acc[mf][r]);
      }
  }
}

// ---------------- flash attention: per (t_blk, bh), 4 waves x 16 t-rows ----------------
__global__ __launch_bounds__(256) void attn_kernel(const ushort_t* __restrict__ q,
                                                   const ushort_t* __restrict__ k,
                                                   const ushort_t* __restrict__ v,
                                                   const ushort_t* __restrict__ B_all,
                                                   const int* __restrict__ mask,
                                                   ushort_t* __restrict__ out) {
  __shared__ ushort_t lK[64][72];
  __shared__ ushort_t lVt[64][72];
  __shared__ ushort_t lP[4][16][72];
  int bh = blockIdx.y, b = bh >> 4, h = bh & 15;
  int t0 = blockIdx.x * 64;
  int tid = threadIdx.x, wave = tid >> 6, lane = tid & 63, l15 = lane & 15, lg = lane >> 4;
  int tw = t0 + wave * 16;
  short8 qf[2];
#pragma unroll
  for (int ks = 0; ks < 2; ++ks)
    qf[ks] = *(const short8*)&q[((size_t)(b * 1024 + tw + l15)) * 1024 + h * 64 + ks * 32 + lg * 8];
  fx4 o[4] = {};
  float mrun = -INFINITY, lsum = 0.f;
  for (int s0 = 0; s0 < 1024; s0 += 64) {
    __syncthreads();
#pragma unroll
    for (int it = 0; it < 2; ++it) {
      int idx = tid + it * 256;  // 0..511
      int r = idx >> 3, c8 = (idx & 7) * 8;
      *(ushort8*)&lK[r][c8] = *(const ushort8*)&k[((size_t)(b * 1024 + s0 + r)) * 1024 + h * 64 + c8];
      ushort8 vv = *(const ushort8*)&v[((size_t)(b * 1024 + s0 + r)) * 1024 + h * 64 + c8];
#pragma unroll
      for (int j = 0; j < 8; ++j) lVt[c8 + j][r] = vv[j];
    }
    __syncthreads();
    // S^T tile: mfma(A=K[s,d], B=Q[t,d]) -> D[s][t]
    fx4 st[4];
#pragma unroll
    for (int mf = 0; mf < 4; ++mf) {
      fx4 c4 = {};
#pragma unroll
      for (int ks = 0; ks < 2; ++ks) {
        short8 kf = *(const short8*)&lK[mf * 16 + l15][ks * 32 + lg * 8];
        c4 = MFMA(kf, qf[ks], c4);
      }
      st[mf] = c4;
    }
    int trow = tw + l15;
    float p[16];
    float mt = -INFINITY;
#pragma unroll
    for (int mf = 0; mf < 4; ++mf) {
      ushortx4 b4 = *(const ushortx4*)&B_all[((size_t)bh * 1024 + trow) * 1024 + s0 + mf * 16 + lg * 4];
      ix4 m4 = *(const ix4*)&mask[((size_t)b * 1024 + trow) * 1024 + s0 + mf * 16 + lg * 4];
#pragma unroll
      for (int r = 0; r < 4; ++r) {
        float sv = (st[mf][r] + bf2f(b4[r])) * 0.125f;
        if (m4[r] == 0) sv = -INFINITY;
        p[mf * 4 + r] = sv;
        mt = fmaxf(mt, sv);
      }
    }
    mt = fmaxf(mt, __shfl_xor(mt, 16));
    mt = fmaxf(mt, __shfl_xor(mt, 32));
    float mnew = fmaxf(mrun, mt);
    float alpha = (mnew == -INFINITY) ? 1.f : __expf(mrun - mnew);
    mrun = mnew;
    float ps = 0.f;
#pragma unroll
    for (int i = 0; i < 16; ++i) {
      float pv = (mnew == -INFINITY) ? 0.f : __expf(p[i] - mnew);
      p[i] = pv;
      ps += pv;
    }
    ps += __shfl_xor(ps, 16);
    ps += __shfl_xor(ps, 32);
    lsum = lsum * alpha + ps;
#pragma unroll
    for (int mf = 0; mf < 4; ++mf) {
      ushortx4 pk4;
#pragma unroll
      for (int r = 0; r < 4; ++r) pk4[r] = f2bf(p[mf * 4 + r]);
      *(ushortx4*)&lP[wave][l15][mf * 16 + lg * 4] = pk4;
    }
    float aw[4];
#pragma unroll
    for (int r = 0; r < 4; ++r) aw[r] = __shfl(alpha, lg * 4 + r);
#pragma unroll
    for (int nf = 0; nf < 4; ++nf)
#pragma unroll
      for (int r = 0; r < 4; ++r) o[nf][r] *= aw[r];
    // PV: mfma(A=P[t,s], B=V[s,d]) -> D[t][d]
#pragma unroll
    for (int ks = 0; ks < 2; ++ks) {
      short8 pf = *(const short8*)&lP[wave][l15][ks * 32 + lg * 8];
#pragma unroll
      for (int nf = 0; nf < 4; ++nf) {
        short8 vf = *(const short8*)&lVt[nf * 16 + l15][ks * 32 + lg * 8];
        o[nf] = MFMA(pf, vf, o[nf]);
      }
    }
  }
  float rl = (lsum > 0.f) ? 1.f / lsum : 0.f;
  float rw[4];
#pragma unroll
  for (int r = 0; r < 4; ++r) rw[r] = __shfl(rl, lg * 4 + r);
#pragma unroll
  for (int nf = 0; nf < 4; ++nf)
#pragma unroll
    for (int r = 0; r < 4; ++r) {
      float val = o[nf][r] * rw[r];
      out[((size_t)(b * 1024 + tw + lg * 4 + r)) * 1024 + h * 64 + nf * 16 + l15] = f2bf(val);
    }
}

extern "C" void kernel_launch(void* const* d_in, const int* in_sizes, int n_in, void* d_out,
                              int out_size, void* d_ws, size_t ws_size, hipStream_t stream) {
  (void)in_sizes; (void)n_in; (void)out_size; (void)ws_size;
  const float* x = (const float*)d_in[0];
  const float* pos_k = (const float*)d_in[1];
  const int* mask = (const int*)d_in[2];
  const float* ln_scale = (const float*)d_in[3];
  const float* ln_bias = (const float*)d_in[4];
  const float* wq = (const float*)d_in[5];
  const float* bq = (const float*)d_in[6];
  const float* wk = (const float*)d_in[7];
  const float* bk = (const float*)d_in[8];
  const float* wv = (const float*)d_in[9];
  const float* bv = (const float*)d_in[10];
  const float* wo = (const float*)d_in[11];
  const float* bo = (const float*)d_in[12];
  float* out = (float*)d_out;
  char* ws = (char*)d_ws;
  const size_t MB = 1ull << 20;
  ushort_t* xn = (ushort_t*)(ws + 0 * MB);
  ushort_t* qb = (ushort_t*)(ws + 16 * MB);
  ushort_t* kb = (ushort_t*)(ws + 32 * MB);
  ushort_t* vb = (ushort_t*)(ws + 48 * MB);
  ushort_t* ao = (ushort_t*)(ws + 64 * MB);
  ushort_t* wqb = (ushort_t*)(ws + 80 * MB);
  ushort_t* wkb = (ushort_t*)(ws + 82 * MB);
  ushort_t* wvb = (ushort_t*)(ws + 84 * MB);
  ushort_t* wob = (ushort_t*)(ws + 86 * MB);
  ushort_t* ball = (ushort_t*)(ws + 88 * MB);  // 256 MB -> needs ws >= 344 MB

  cvt_kernel<<<1024, 256, 0, stream>>>(wq, wqb, 262144);
  cvt_kernel<<<1024, 256, 0, stream>>>(wk, wkb, 262144);
  cvt_kernel<<<1024, 256, 0, stream>>>(wv, wvb, 262144);
  cvt_kernel<<<1024, 256, 0, stream>>>(wo, wob, 262144);
  ln_kernel<<<8192, 256, 0, stream>>>(x, ln_scale, ln_bias, xn);
  dim3 gg(8, 64);
  gemm_bt<0><<<gg, 256, 0, stream>>>(xn, wqb, bq, qb, 8192, 1024, 1024);
  gemm_bt<0><<<gg, 256, 0, stream>>>(xn, wkb, bk, kb, 8192, 1024, 1024);
  gemm_bt<0><<<gg, 256, 0, stream>>>(xn, wvb, bv, vb, 8192, 1024, 1024);
  ball_kernel<<<1024, 256, 0, stream>>>(qb, pos_k, ball);
  attn_kernel<<<dim3(16, 128), 256, 0, stream>>>(qb, kb, vb, ball, mask, ao);
  gemm_bt<1><<<gg, 256, 0, stream>>>(ao, wob, bo, out, 8192, 1024, 1024);
}

// Round 2
// 566.593 us; speedup vs baseline: 1.1027x; 1.1027x over previous
//
#include <hip/hip_runtime.h>
#include <hip/hip_bf16.h>

typedef unsigned short ushort_t;
typedef short short8 __attribute__((ext_vector_type(8)));
typedef unsigned short ushort8 __attribute__((ext_vector_type(8)));
typedef unsigned short ushortx4 __attribute__((ext_vector_type(4)));
typedef float fx4 __attribute__((ext_vector_type(4)));
typedef int ix4 __attribute__((ext_vector_type(4)));

#define MFMA(a, b, c) __builtin_amdgcn_mfma_f32_16x16x32_bf16((a), (b), (c), 0, 0, 0)

__device__ __forceinline__ ushort_t f2bf(float f) {
  __hip_bfloat16 h = __float2bfloat16(f);
  return *(ushort_t*)&h;
}
__device__ __forceinline__ float bf2f(ushort_t h) {
  union { unsigned u; float f; } c; c.u = ((unsigned)h) << 16;
  return c.f;
}
__device__ __forceinline__ void gload16(const ushort_t* g, ushort_t* l) {
  __builtin_amdgcn_global_load_lds((const __attribute__((address_space(1))) void*)g,
                                   (__attribute__((address_space(3))) void*)l, 16, 0, 0);
}

// ---------------- f32 -> bf16 convert for the 4 weight matrices ----------------
__global__ __launch_bounds__(256) void cvt4_kernel(const float* __restrict__ s0,
                                                   const float* __restrict__ s1,
                                                   const float* __restrict__ s2,
                                                   const float* __restrict__ s3,
                                                   ushort_t* __restrict__ d0,
                                                   ushort_t* __restrict__ d1,
                                                   ushort_t* __restrict__ d2,
                                                   ushort_t* __restrict__ d3) {
  int bi = blockIdx.x;
  const float* src = (bi < 1024) ? s0 : (bi < 2048) ? s1 : (bi < 3072) ? s2 : s3;
  ushort_t* dst = (bi < 1024) ? d0 : (bi < 2048) ? d1 : (bi < 3072) ? d2 : d3;
  int i = (bi & 1023) * 256 + threadIdx.x;
  fx4 v = *(const fx4*)&src[(size_t)i * 4];
  ushortx4 o;
#pragma unroll
  for (int j = 0; j < 4; ++j) o[j] = f2bf(v[j]);
  *(ushortx4*)&dst[(size_t)i * 4] = o;
}

// ---------------- LayerNorm: x (f32, row=1024) -> xn (bf16) ----------------
__global__ __launch_bounds__(256) void ln_kernel(const float* __restrict__ x,
                                                 const float* __restrict__ sc,
                                                 const float* __restrict__ bi,
                                                 ushort_t* __restrict__ xn) {
  __shared__ float red[8];
  int row = blockIdx.x, tid = threadIdx.x;
  const float* xr = x + (size_t)row * 1024;
  fx4 v = *(const fx4*)&xr[tid * 4];
  float s = v[0] + v[1] + v[2] + v[3];
  float s2 = v[0] * v[0] + v[1] * v[1] + v[2] * v[2] + v[3] * v[3];
#pragma unroll
  for (int m = 32; m >= 1; m >>= 1) {
    s += __shfl_xor(s, m);
    s2 += __shfl_xor(s2, m);
  }
  int wave = tid >> 6;
  if ((tid & 63) == 0) { red[wave * 2] = s; red[wave * 2 + 1] = s2; }
  __syncthreads();
  s = red[0] + red[2] + red[4] + red[6];
  s2 = red[1] + red[3] + red[5] + red[7];
  float mu = s * (1.f / 1024.f);
  float var = s2 * (1.f / 1024.f) - mu * mu;
  float rs = rsqrtf(var + 1e-5f);
  fx4 scv = *(const fx4*)&sc[tid * 4];
  fx4 biv = *(const fx4*)&bi[tid * 4];
  ushortx4 o;
#pragma unroll
  for (int j = 0; j < 4; ++j) o[j] = f2bf((v[j] - mu) * rs * scv[j] + biv[j]);
  *(ushortx4*)&xn[(size_t)row * 1024 + tid * 4] = o;
}

// ---------------- mask (int32) -> 1 bit per (b,t,s) ----------------
__global__ __launch_bounds__(256) void maskpack_kernel(const int* __restrict__ mask,
                                                       unsigned* __restrict__ bits) {
  __shared__ unsigned char nib[256];
  int row = blockIdx.x, tid = threadIdx.x;
  ix4 m = *(const ix4*)&mask[(size_t)row * 1024 + tid * 4];
  nib[tid] = (unsigned char)((m[0] != 0 ? 1 : 0) | (m[1] != 0 ? 2 : 0) |
                             (m[2] != 0 ? 4 : 0) | (m[3] != 0 ? 8 : 0));
  __syncthreads();
  if (tid < 32) {
    unsigned w = 0;
#pragma unroll
    for (int j = 0; j < 8; ++j) w |= ((unsigned)nib[tid * 8 + j]) << (j * 4);
    bits[(size_t)row * 32 + tid] = w;
  }
}

// ---------------- GEMM: C[M][N] = A[M][K] @ B[N][K]^T + bias ----------------
// m97 pattern: 128x128 tile, BK=32, linear LDS, global_load_lds width-16.
template <int F32OUT>
__global__ __launch_bounds__(256) void gemm_bt(const ushort_t* __restrict__ A,
                                               const ushort_t* __restrict__ B,
                                               const float* __restrict__ bias, void* C,
                                               int M, int N, int K) {
  __shared__ ushort_t lA[4096];  // [128][32] linear
  __shared__ ushort_t lB[4096];
  int bm = blockIdx.y * 128, bn = blockIdx.x * 128;
  int tid = threadIdx.x;
  int wave = tid >> 6, lane = tid & 63;
  int wm = (wave >> 1) * 64, wn = (wave & 1) * 64;
  int l15 = lane & 15, lg = lane >> 4;
  int r0 = tid >> 2, c0 = (tid & 3) * 8;
  int g1 = 256 + tid, r1 = g1 >> 2, c1 = (g1 & 3) * 8;
  int lb0 = (wave * 64) * 8;          // LDS element base, instr 0
  int lb1 = (256 + wave * 64) * 8;    // instr 1
  fx4 acc[4][4] = {};
  for (int k0 = 0; k0 < K; k0 += 32) {
    __syncthreads();
    gload16(&A[(size_t)(bm + r0) * K + k0 + c0], &lA[lb0]);
    gload16(&A[(size_t)(bm + r1) * K + k0 + c1], &lA[lb1]);
    gload16(&B[(size_t)(bn + r0) * K + k0 + c0], &lB[lb0]);
    gload16(&B[(size_t)(bn + r1) * K + k0 + c1], &lB[lb1]);
    __syncthreads();
    short8 af[4], bf[4];
#pragma unroll
    for (int i = 0; i < 4; ++i) af[i] = *(const short8*)&lA[(wm + i * 16 + l15) * 32 + lg * 8];
#pragma unroll
    for (int i = 0; i < 4; ++i) bf[i] = *(const short8*)&lB[(wn + i * 16 + l15) * 32 + lg * 8];
#pragma unroll
    for (int i = 0; i < 4; ++i)
#pragma unroll
      for (int j = 0; j < 4; ++j) acc[i][j] = MFMA(af[i], bf[j], acc[i][j]);
  }
#pragma unroll
  for (int j = 0; j < 4; ++j) {
    int n = bn + wn + j * 16 + l15;
    float bv = bias[n];
#pragma unroll
    for (int i = 0; i < 4; ++i) {
      int mr = bm + wm + i * 16 + lg * 4;
#pragma unroll
      for (int r = 0; r < 4; ++r) {
        float val = acc[i][j][r] + bv;
        if (F32OUT)
          ((float*)C)[(size_t)(mr + r) * N + n] = val;
        else
          ((ushort_t*)C)[(size_t)(mr + r) * N + n] = f2bf(val);
      }
    }
  }
}

// ---------------- B_all[bh][t][s] = sum_d q[b,t,h*64+d] * pos_k[t,s,d] ----------------
// Swapped operands: D[row=s][col=bh] -> each lane stores 4 consecutive s (8 B) per bh.
// No LDS, no barriers. Grid (2 s-halves, 1024 t), 4 waves x 128 s each.
__global__ __launch_bounds__(256) void ball_kernel(const ushort_t* __restrict__ q,
                                                   const float* __restrict__ pos_k,
                                                   ushort_t* __restrict__ B_all) {
  int t = blockIdx.y, sx = blockIdx.x;
  int tid = threadIdx.x, wave = tid >> 6, lane = tid & 63, l15 = lane & 15, lg = lane >> 4;
  // q fragments (B operand): bq[j][ks] = q[b=j, t, h=l15, d=ks*32+lg*8 ..+8]
  short8 bq[8][2];
#pragma unroll
  for (int j = 0; j < 8; ++j)
#pragma unroll
    for (int ks = 0; ks < 2; ++ks)
      bq[j][ks] = *(const short8*)&q[((size_t)(j * 1024 + t)) * 1024 + l15 * 64 + ks * 32 + lg * 8];
  const float* pk = pos_k + (size_t)t * 65536;
  int s_wave = sx * 512 + wave * 128;
#pragma unroll 2
  for (int ch = 0; ch < 8; ++ch) {
    int sb = s_wave + ch * 16;
    const float* ps = pk + (size_t)(sb + l15) * 64 + lg * 8;
    fx4 p0 = *(const fx4*)ps;
    fx4 p1 = *(const fx4*)(ps + 4);
    fx4 p2 = *(const fx4*)(ps + 32);
    fx4 p3 = *(const fx4*)(ps + 36);
    short8 af0, af1;
#pragma unroll
    for (int j = 0; j < 4; ++j) {
      af0[j] = (short)f2bf(p0[j]); af0[j + 4] = (short)f2bf(p1[j]);
      af1[j] = (short)f2bf(p2[j]); af1[j + 4] = (short)f2bf(p3[j]);
    }
    fx4 acc[8];
#pragma unroll
    for (int j = 0; j < 8; ++j) acc[j] = fx4{0.f, 0.f, 0.f, 0.f};
#pragma unroll
    for (int j = 0; j < 8; ++j) {
      acc[j] = MFMA(af0, bq[j][0], acc[j]);
      acc[j] = MFMA(af1, bq[j][1], acc[j]);
    }
#pragma unroll
    for (int j = 0; j < 8; ++j) {
      ushortx4 o;
#pragma unroll
      for (int r = 0; r < 4; ++r) o[r] = f2bf(acc[j][r]);
      *(ushortx4*)&B_all[((size_t)(j * 16 + l15) * 1024 + t) * 1024 + sb + lg * 4] = o;
    }
  }
}

// ---------------- flash attention: per (t_blk, bh), 4 waves x 16 t-rows ----------------
__global__ __launch_bounds__(256) void attn_kernel(const ushort_t* __restrict__ q,
                                                   const ushort_t* __restrict__ k,
                                                   const ushort_t* __restrict__ v,
                                                   const ushort_t* __restrict__ B_all,
                                                   const unsigned* __restrict__ mbits,
                                                   ushort_t* __restrict__ out) {
  __shared__ ushort_t lK[64][72];
  __shared__ ushort_t lVt[64][72];
  __shared__ ushort_t lP[4][16][72];
  int bh = blockIdx.y, b = bh >> 4, h = bh & 15;
  int t0 = blockIdx.x * 64;
  int tid = threadIdx.x, wave = tid >> 6, lane = tid & 63, l15 = lane & 15, lg = lane >> 4;
  int tw = t0 + wave * 16;
  short8 qf[2];
#pragma unroll
  for (int ks = 0; ks < 2; ++ks)
    qf[ks] = *(const short8*)&q[((size_t)(b * 1024 + tw + l15)) * 1024 + h * 64 + ks * 32 + lg * 8];
  fx4 o[4] = {};
  float mrun = -INFINITY, lsum = 0.f;
  int trow = tw + l15;
  const unsigned* mrow = &mbits[((size_t)b * 1024 + trow) * 32];
  for (int s0 = 0; s0 < 1024; s0 += 64) {
    __syncthreads();
#pragma unroll
    for (int it = 0; it < 2; ++it) {
      int idx = tid + it * 256;  // 0..511
      int r = idx >> 3, c8 = (idx & 7) * 8;
      *(ushort8*)&lK[r][c8] = *(const ushort8*)&k[((size_t)(b * 1024 + s0 + r)) * 1024 + h * 64 + c8];
      ushort8 vv = *(const ushort8*)&v[((size_t)(b * 1024 + s0 + r)) * 1024 + h * 64 + c8];
#pragma unroll
      for (int j = 0; j < 8; ++j) lVt[c8 + j][r] = vv[j];
    }
    __syncthreads();
    // S^T tile: mfma(A=K[s,d], B=Q[t,d]) -> D[s][t]
    fx4 st[4];
#pragma unroll
    for (int mf = 0; mf < 4; ++mf) {
      fx4 c4 = {};
#pragma unroll
      for (int ks = 0; ks < 2; ++ks) {
        short8 kf = *(const short8*)&lK[mf * 16 + l15][ks * 32 + lg * 8];
        c4 = MFMA(kf, qf[ks], c4);
      }
      st[mf] = c4;
    }
    uint2 mw = *(const uint2*)&mrow[s0 >> 5];
    unsigned long long wb = ((unsigned long long)mw.y << 32) | mw.x;
    float p[16];
    float mt = -INFINITY;
#pragma unroll
    for (int mf = 0; mf < 4; ++mf) {
      ushortx4 b4 = *(const ushortx4*)&B_all[((size_t)bh * 1024 + trow) * 1024 + s0 + mf * 16 + lg * 4];
#pragma unroll
      for (int r = 0; r < 4; ++r) {
        float sv = (st[mf][r] + bf2f(b4[r])) * 0.125f;
        int sl = mf * 16 + lg * 4 + r;
        if (!((wb >> sl) & 1ull)) sv = -INFINITY;
        p[mf * 4 + r] = sv;
        mt = fmaxf(mt, sv);
      }
    }
    mt = fmaxf(mt, __shfl_xor(mt, 16));
    mt = fmaxf(mt, __shfl_xor(mt, 32));
    float mnew = fmaxf(mrun, mt);
    float alpha = (mnew == -INFINITY) ? 1.f : __expf(mrun - mnew);
    mrun = mnew;
    float ps = 0.f;
#pragma unroll
    for (int i = 0; i < 16; ++i) {
      float pv = (mnew == -INFINITY) ? 0.f : __expf(p[i] - mnew);
      p[i] = pv;
      ps += pv;
    }
    ps += __shfl_xor(ps, 16);
    ps += __shfl_xor(ps, 32);
    lsum = lsum * alpha + ps;
#pragma unroll
    for (int mf = 0; mf < 4; ++mf) {
      ushortx4 pk4;
#pragma unroll
      for (int r = 0; r < 4; ++r) pk4[r] = f2bf(p[mf * 4 + r]);
      *(ushortx4*)&lP[wave][l15][mf * 16 + lg * 4] = pk4;
    }
    float aw[4];
#pragma unroll
    for (int r = 0; r < 4; ++r) aw[r] = __shfl(alpha, lg * 4 + r);
#pragma unroll
    for (int nf = 0; nf < 4; ++nf)
#pragma unroll
      for (int r = 0; r < 4; ++r) o[nf][r] *= aw[r];
    // PV: mfma(A=P[t,s], B=V[s,d]) -> D[t][d]
#pragma unroll
    for (int ks = 0; ks < 2; ++ks) {
      short8 pf = *(const short8*)&lP[wave][l15][ks * 32 + lg * 8];
#pragma unroll
      for (int nf = 0; nf < 4; ++nf) {
        short8 vf = *(const short8*)&lVt[nf * 16 + l15][ks * 32 + lg * 8];
        o[nf] = MFMA(pf, vf, o[nf]);
      }
    }
  }
  float rl = (lsum > 0.f) ? 1.f / lsum : 0.f;
  float rw[4];
#pragma unroll
  for (int r = 0; r < 4; ++r) rw[r] = __shfl(rl, lg * 4 + r);
#pragma unroll
  for (int nf = 0; nf < 4; ++nf)
#pragma unroll
    for (int r = 0; r < 4; ++r) {
      float val = o[nf][r] * rw[r];
      out[((size_t)(b * 1024 + tw + lg * 4 + r)) * 1024 + h * 64 + nf * 16 + l15] = f2bf(val);
    }
}

extern "C" void kernel_launch(void* const* d_in, const int* in_sizes, int n_in, void* d_out,
                              int out_size, void* d_ws, size_t ws_size, hipStream_t stream) {
  (void)in_sizes; (void)n_in; (void)out_size; (void)ws_size;
  const float* x = (const float*)d_in[0];
  const float* pos_k = (const float*)d_in[1];
  const int* mask = (const int*)d_in[2];
  const float* ln_scale = (const float*)d_in[3];
  const float* ln_bias = (const float*)d_in[4];
  const float* wq = (const float*)d_in[5];
  const float* bq = (const float*)d_in[6];
  const float* wk = (const float*)d_in[7];
  const float* bk = (const float*)d_in[8];
  const float* wv = (const float*)d_in[9];
  const float* bv = (const float*)d_in[10];
  const float* wo = (const float*)d_in[11];
  const float* bo = (const float*)d_in[12];
  float* out = (float*)d_out;
  char* ws = (char*)d_ws;
  const size_t MB = 1ull << 20;
  ushort_t* xn = (ushort_t*)(ws + 0 * MB);   // 16 MB; region reused for mbits after QKV
  ushort_t* qb = (ushort_t*)(ws + 16 * MB);
  ushort_t* kb = (ushort_t*)(ws + 32 * MB);
  ushort_t* vb = (ushort_t*)(ws + 48 * MB);
  ushort_t* ao = (ushort_t*)(ws + 64 * MB);
  ushort_t* wqb = (ushort_t*)(ws + 80 * MB);
  ushort_t* wkb = (ushort_t*)(ws + 82 * MB);
  ushort_t* wvb = (ushort_t*)(ws + 84 * MB);
  ushort_t* wob = (ushort_t*)(ws + 86 * MB);
  ushort_t* ball = (ushort_t*)(ws + 88 * MB);  // 256 MB -> ws >= 344 MB (verified round 0)
  unsigned* mbits = (unsigned*)(ws + 0 * MB);  // 1 MB, reuses xn region (dead after QKV)

  cvt4_kernel<<<4096, 256, 0, stream>>>(wq, wk, wv, wo, wqb, wkb, wvb, wob);
  ln_kernel<<<8192, 256, 0, stream>>>(x, ln_scale, ln_bias, xn);
  dim3 gg(8, 64);
  gemm_bt<0><<<gg, 256, 0, stream>>>(xn, wqb, bq, qb, 8192, 1024, 1024);
  gemm_bt<0><<<gg, 256, 0, stream>>>(xn, wkb, bk, kb, 8192, 1024, 1024);
  gemm_bt<0><<<gg, 256, 0, stream>>>(xn, wvb, bv, vb, 8192, 1024, 1024);
  maskpack_kernel<<<8192, 256, 0, stream>>>(mask, mbits);  // after QKV: xn region now free
  ball_kernel<<<dim3(2, 1024), 256, 0, stream>>>(qb, pos_k, ball);
  attn_kernel<<<dim3(16, 128), 256, 0, stream>>>(qb, kb, vb, ball, mbits, ao);
  gemm_bt<1><<<gg, 256, 0, stream>>>(ao, wob, bo, out, 8192, 1024, 1024);
}

// Round 4
// 549.789 us; speedup vs baseline: 1.1365x; 1.0306x over previous
//
#include <hip/hip_runtime.h>
#include <hip/hip_bf16.h>

typedef unsigned short ushort_t;
typedef short short8 __attribute__((ext_vector_type(8)));
typedef unsigned short ushort8 __attribute__((ext_vector_type(8)));
typedef unsigned short ushortx4 __attribute__((ext_vector_type(4)));
typedef float fx4 __attribute__((ext_vector_type(4)));
typedef int ix4 __attribute__((ext_vector_type(4)));

#define MFMA(a, b, c) __builtin_amdgcn_mfma_f32_16x16x32_bf16((a), (b), (c), 0, 0, 0)

__device__ __forceinline__ ushort_t f2bf(float f) {
  __hip_bfloat16 h = __float2bfloat16(f);
  return *(ushort_t*)&h;
}
__device__ __forceinline__ float bf2f(ushort_t h) {
  union { unsigned u; float f; } c; c.u = ((unsigned)h) << 16;
  return c.f;
}
__device__ __forceinline__ void gload16(const ushort_t* g, ushort_t* l) {
  __builtin_amdgcn_global_load_lds((const __attribute__((address_space(1))) void*)g,
                                   (__attribute__((address_space(3))) void*)l, 16, 0, 0);
}

// ---------------- f32 -> bf16 convert for the 4 weight matrices ----------------
__global__ __launch_bounds__(256) void cvt4_kernel(const float* __restrict__ s0,
                                                   const float* __restrict__ s1,
                                                   const float* __restrict__ s2,
                                                   const float* __restrict__ s3,
                                                   ushort_t* __restrict__ d0,
                                                   ushort_t* __restrict__ d1,
                                                   ushort_t* __restrict__ d2,
                                                   ushort_t* __restrict__ d3) {
  int bi = blockIdx.x;
  const float* src = (bi < 1024) ? s0 : (bi < 2048) ? s1 : (bi < 3072) ? s2 : s3;
  ushort_t* dst = (bi < 1024) ? d0 : (bi < 2048) ? d1 : (bi < 3072) ? d2 : d3;
  int i = (bi & 1023) * 256 + threadIdx.x;
  fx4 v = *(const fx4*)&src[(size_t)i * 4];
  ushortx4 o;
#pragma unroll
  for (int j = 0; j < 4; ++j) o[j] = f2bf(v[j]);
  *(ushortx4*)&dst[(size_t)i * 4] = o;
}

// ---------------- LayerNorm: x (f32, row=1024) -> xn (bf16) ----------------
__global__ __launch_bounds__(256) void ln_kernel(const float* __restrict__ x,
                                                 const float* __restrict__ sc,
                                                 const float* __restrict__ bi,
                                                 ushort_t* __restrict__ xn) {
  __shared__ float red[8];
  int row = blockIdx.x, tid = threadIdx.x;
  const float* xr = x + (size_t)row * 1024;
  fx4 v = *(const fx4*)&xr[tid * 4];
  float s = v[0] + v[1] + v[2] + v[3];
  float s2 = v[0] * v[0] + v[1] * v[1] + v[2] * v[2] + v[3] * v[3];
#pragma unroll
  for (int m = 32; m >= 1; m >>= 1) {
    s += __shfl_xor(s, m);
    s2 += __shfl_xor(s2, m);
  }
  int wave = tid >> 6;
  if ((tid & 63) == 0) { red[wave * 2] = s; red[wave * 2 + 1] = s2; }
  __syncthreads();
  s = red[0] + red[2] + red[4] + red[6];
  s2 = red[1] + red[3] + red[5] + red[7];
  float mu = s * (1.f / 1024.f);
  float var = s2 * (1.f / 1024.f) - mu * mu;
  float rs = rsqrtf(var + 1e-5f);
  fx4 scv = *(const fx4*)&sc[tid * 4];
  fx4 biv = *(const fx4*)&bi[tid * 4];
  ushortx4 o;
#pragma unroll
  for (int j = 0; j < 4; ++j) o[j] = f2bf((v[j] - mu) * rs * scv[j] + biv[j]);
  *(ushortx4*)&xn[(size_t)row * 1024 + tid * 4] = o;
}

// ---------------- mask (int32) -> 1 bit per (b,t,s) ----------------
__global__ __launch_bounds__(256) void maskpack_kernel(const int* __restrict__ mask,
                                                       unsigned* __restrict__ bits) {
  __shared__ unsigned char nib[256];
  int row = blockIdx.x, tid = threadIdx.x;
  ix4 m = *(const ix4*)&mask[(size_t)row * 1024 + tid * 4];
  nib[tid] = (unsigned char)((m[0] != 0 ? 1 : 0) | (m[1] != 0 ? 2 : 0) |
                             (m[2] != 0 ? 4 : 0) | (m[3] != 0 ? 8 : 0));
  __syncthreads();
  if (tid < 32) {
    unsigned w = 0;
#pragma unroll
    for (int j = 0; j < 8; ++j) w |= ((unsigned)nib[tid * 8 + j]) << (j * 4);
    bits[(size_t)row * 32 + tid] = w;
  }
}

// ---------------- GEMM: C[M][N] = A[M][K] @ B[N][K]^T + bias ----------------
// m97 pattern: 128x128 tile, BK=32, linear LDS, global_load_lds width-16.
template <int F32OUT>
__global__ __launch_bounds__(256) void gemm_bt(const ushort_t* __restrict__ A,
                                               const ushort_t* __restrict__ B,
                                               const float* __restrict__ bias, void* C,
                                               int M, int N, int K) {
  __shared__ ushort_t lA[4096];  // [128][32] linear
  __shared__ ushort_t lB[4096];
  int bm = blockIdx.y * 128, bn = blockIdx.x * 128;
  int tid = threadIdx.x;
  int wave = tid >> 6, lane = tid & 63;
  int wm = (wave >> 1) * 64, wn = (wave & 1) * 64;
  int l15 = lane & 15, lg = lane >> 4;
  int r0 = tid >> 2, c0 = (tid & 3) * 8;
  int g1 = 256 + tid, r1 = g1 >> 2, c1 = (g1 & 3) * 8;
  int lb0 = (wave * 64) * 8;          // LDS element base, instr 0
  int lb1 = (256 + wave * 64) * 8;    // instr 1
  fx4 acc[4][4] = {};
  for (int k0 = 0; k0 < K; k0 += 32) {
    __syncthreads();
    gload16(&A[(size_t)(bm + r0) * K + k0 + c0], &lA[lb0]);
    gload16(&A[(size_t)(bm + r1) * K + k0 + c1], &lA[lb1]);
    gload16(&B[(size_t)(bn + r0) * K + k0 + c0], &lB[lb0]);
    gload16(&B[(size_t)(bn + r1) * K + k0 + c1], &lB[lb1]);
    __syncthreads();
    short8 af[4], bf[4];
#pragma unroll
    for (int i = 0; i < 4; ++i) af[i] = *(const short8*)&lA[(wm + i * 16 + l15) * 32 + lg * 8];
#pragma unroll
    for (int i = 0; i < 4; ++i) bf[i] = *(const short8*)&lB[(wn + i * 16 + l15) * 32 + lg * 8];
#pragma unroll
    for (int i = 0; i < 4; ++i)
#pragma unroll
      for (int j = 0; j < 4; ++j) acc[i][j] = MFMA(af[i], bf[j], acc[i][j]);
  }
#pragma unroll
  for (int j = 0; j < 4; ++j) {
    int n = bn + wn + j * 16 + l15;
    float bv = bias[n];
#pragma unroll
    for (int i = 0; i < 4; ++i) {
      int mr = bm + wm + i * 16 + lg * 4;
#pragma unroll
      for (int r = 0; r < 4; ++r) {
        float val = acc[i][j][r] + bv;
        if (F32OUT)
          ((float*)C)[(size_t)(mr + r) * N + n] = val;
        else
          ((ushort_t*)C)[(size_t)(mr + r) * N + n] = f2bf(val);
      }
    }
  }
}

// ---------------- B_all[bh][t][s] = sum_d q[b,t,h*64+d] * pos_k[t,s,d] ----------------
// v3: q staged in LDS (XOR-swizzled, read per chunk) -> VGPRs freed for a 2-deep
// register software pipeline on the pos_k loads. No barriers in the main loop.
// Grid (2 s-halves, 1024 t), 4 waves x 128 s each. D[row=s][col=bh].
__global__ __launch_bounds__(256) void ball_kernel(const ushort_t* __restrict__ q,
                                                   const float* __restrict__ pos_k,
                                                   ushort_t* __restrict__ B_all) {
  __shared__ ushort_t lq[128 * 64];  // rows of 128 B, col-byte ^= (row&7)<<4
  int t = blockIdx.y, sx = blockIdx.x;
  int tid = threadIdx.x, wave = tid >> 6, lane = tid & 63, l15 = lane & 15, lg = lane >> 4;

  const float* pk = pos_k + (size_t)t * 65536;
  int sw = sx * 512 + wave * 128;
  const float* base = pk + (size_t)(sw + l15) * 64 + lg * 8;

  fx4 a0, a1, a2, a3, b0, b1, b2, b3;
#define LOADSET(v0, v1, v2, v3, c)                \
  {                                               \
    const float* p_ = base + (size_t)(c) * 1024;  \
    v0 = *(const fx4*)p_;                         \
    v1 = *(const fx4*)(p_ + 4);                   \
    v2 = *(const fx4*)(p_ + 32);                  \
    v3 = *(const fx4*)(p_ + 36);                  \
  }
  LOADSET(a0, a1, a2, a3, 0)
  LOADSET(b0, b1, b2, b3, 1)

  // stage q[t]: 128 bh-rows x 64 bf16 (16 KB), swizzled
#pragma unroll
  for (int it = 0; it < 4; ++it) {
    int u = tid + it * 256;           // 0..1023 16B-units
    int row = u >> 3, cu = u & 7;     // row=bh, cu=16B col unit
    ushort8 vv = *(const ushort8*)&q[((size_t)((row >> 4) * 1024 + t)) * 1024 + (row & 15) * 64 + cu * 8];
    *(ushort8*)&lq[(row * 128 + ((cu * 16) ^ ((row & 7) << 4))) >> 1] = vv;
  }
  __syncthreads();

#define CVT(af0, af1, v0, v1, v2, v3)                              \
  {                                                                \
    _Pragma("unroll") for (int j_ = 0; j_ < 4; ++j_) {             \
      af0[j_] = (short)f2bf(v0[j_]); af0[j_ + 4] = (short)f2bf(v1[j_]); \
      af1[j_] = (short)f2bf(v2[j_]); af1[j_ + 4] = (short)f2bf(v3[j_]); \
    }                                                              \
  }

#define COMPUTE(af0, af1, c)                                                        \
  {                                                                                 \
    int sb_ = sw + (c) * 16;                                                        \
    fx4 z_ = {};                                                                    \
    fx4 acc_[8];                                                                    \
    _Pragma("unroll") for (int j_ = 0; j_ < 8; ++j_) {                              \
      int row_ = j_ * 16 + l15;                                                     \
      int cb_ = (row_ & 7) << 4;                                                    \
      short8 q0_ = *(const short8*)&lq[(row_ * 128 + ((lg * 16) ^ cb_)) >> 1];      \
      short8 q1_ = *(const short8*)&lq[(row_ * 128 + ((64 + lg * 16) ^ cb_)) >> 1]; \
      fx4 t_ = MFMA(af0, q0_, z_);                                                  \
      acc_[j_] = MFMA(af1, q1_, t_);                                                \
    }                                                                               \
    _Pragma("unroll") for (int j_ = 0; j_ < 8; ++j_) {                              \
      ushortx4 o_;                                                                  \
      _Pragma("unroll") for (int r_ = 0; r_ < 4; ++r_) o_[r_] = f2bf(acc_[j_][r_]); \
      *(ushortx4*)&B_all[((size_t)(j_ * 16 + l15) * 1024 + t) * 1024 + sb_ + lg * 4] = o_; \
    }                                                                               \
  }

#pragma unroll
  for (int cc = 0; cc < 4; ++cc) {
    int c = cc * 2;
    short8 af0, af1;
    CVT(af0, af1, a0, a1, a2, a3)
    if (cc < 3) LOADSET(a0, a1, a2, a3, c + 2)
    COMPUTE(af0, af1, c)
    short8 bf0, bf1;
    CVT(bf0, bf1, b0, b1, b2, b3)
    if (cc < 3) LOADSET(b0, b1, b2, b3, c + 3)
    COMPUTE(bf0, bf1, c + 1)
  }
#undef LOADSET
#undef CVT
#undef COMPUTE
}

// ---------------- flash attention: per (t_blk, bh), 4 waves x 16 t-rows ----------------
__global__ __launch_bounds__(256) void attn_kernel(const ushort_t* __restrict__ q,
                                                   const ushort_t* __restrict__ k,
                                                   const ushort_t* __restrict__ v,
                                                   const ushort_t* __restrict__ B_all,
                                                   const unsigned* __restrict__ mbits,
                                                   ushort_t* __restrict__ out) {
  __shared__ ushort_t lK[64][72];
  __shared__ ushort_t lVt[64][72];
  __shared__ ushort_t lP[4][16][72];
  int bh = blockIdx.y, b = bh >> 4, h = bh & 15;
  int t0 = blockIdx.x * 64;
  int tid = threadIdx.x, wave = tid >> 6, lane = tid & 63, l15 = lane & 15, lg = lane >> 4;
  int tw = t0 + wave * 16;
  short8 qf[2];
#pragma unroll
  for (int ks = 0; ks < 2; ++ks)
    qf[ks] = *(const short8*)&q[((size_t)(b * 1024 + tw + l15)) * 1024 + h * 64 + ks * 32 + lg * 8];
  fx4 o[4] = {};
  float mrun = -INFINITY, lsum = 0.f;
  int trow = tw + l15;
  const unsigned* mrow = &mbits[((size_t)b * 1024 + trow) * 32];
  for (int s0 = 0; s0 < 1024; s0 += 64) {
    __syncthreads();
#pragma unroll
    for (int it = 0; it < 2; ++it) {
      int idx = tid + it * 256;  // 0..511
      int r = idx >> 3, c8 = (idx & 7) * 8;
      *(ushort8*)&lK[r][c8] = *(const ushort8*)&k[((size_t)(b * 1024 + s0 + r)) * 1024 + h * 64 + c8];
      ushort8 vv = *(const ushort8*)&v[((size_t)(b * 1024 + s0 + r)) * 1024 + h * 64 + c8];
#pragma unroll
      for (int j = 0; j < 8; ++j) lVt[c8 + j][r] = vv[j];
    }
    __syncthreads();
    // S^T tile: mfma(A=K[s,d], B=Q[t,d]) -> D[s][t]
    fx4 st[4];
#pragma unroll
    for (int mf = 0; mf < 4; ++mf) {
      fx4 c4 = {};
#pragma unroll
      for (int ks = 0; ks < 2; ++ks) {
        short8 kf = *(const short8*)&lK[mf * 16 + l15][ks * 32 + lg * 8];
        c4 = MFMA(kf, qf[ks], c4);
      }
      st[mf] = c4;
    }
    uint2 mw = *(const uint2*)&mrow[s0 >> 5];
    unsigned long long wb = ((unsigned long long)mw.y << 32) | mw.x;
    float p[16];
    float mt = -INFINITY;
#pragma unroll
    for (int mf = 0; mf < 4; ++mf) {
      ushortx4 b4 = *(const ushortx4*)&B_all[((size_t)bh * 1024 + trow) * 1024 + s0 + mf * 16 + lg * 4];
#pragma unroll
      for (int r = 0; r < 4; ++r) {
        float sv = (st[mf][r] + bf2f(b4[r])) * 0.125f;
        int sl = mf * 16 + lg * 4 + r;
        if (!((wb >> sl) & 1ull)) sv = -INFINITY;
        p[mf * 4 + r] = sv;
        mt = fmaxf(mt, sv);
      }
    }
    mt = fmaxf(mt, __shfl_xor(mt, 16));
    mt = fmaxf(mt, __shfl_xor(mt, 32));
    float mnew = fmaxf(mrun, mt);
    float alpha = (mnew == -INFINITY) ? 1.f : __expf(mrun - mnew);
    mrun = mnew;
    float ps = 0.f;
#pragma unroll
    for (int i = 0; i < 16; ++i) {
      float pv = (mnew == -INFINITY) ? 0.f : __expf(p[i] - mnew);
      p[i] = pv;
      ps += pv;
    }
    ps += __shfl_xor(ps, 16);
    ps += __shfl_xor(ps, 32);
    lsum = lsum * alpha + ps;
#pragma unroll
    for (int mf = 0; mf < 4; ++mf) {
      ushortx4 pk4;
#pragma unroll
      for (int r = 0; r < 4; ++r) pk4[r] = f2bf(p[mf * 4 + r]);
      *(ushortx4*)&lP[wave][l15][mf * 16 + lg * 4] = pk4;
    }
    float aw[4];
#pragma unroll
    for (int r = 0; r < 4; ++r) aw[r] = __shfl(alpha, lg * 4 + r);
#pragma unroll
    for (int nf = 0; nf < 4; ++nf)
#pragma unroll
      for (int r = 0; r < 4; ++r) o[nf][r] *= aw[r];
    // PV: mfma(A=P[t,s], B=V[s,d]) -> D[t][d]
#pragma unroll
    for (int ks = 0; ks < 2; ++ks) {
      short8 pf = *(const short8*)&lP[wave][l15][ks * 32 + lg * 8];
#pragma unroll
      for (int nf = 0; nf < 4; ++nf) {
        short8 vf = *(const short8*)&lVt[nf * 16 + l15][ks * 32 + lg * 8];
        o[nf] = MFMA(pf, vf, o[nf]);
      }
    }
  }
  float rl = (lsum > 0.f) ? 1.f / lsum : 0.f;
  float rw[4];
#pragma unroll
  for (int r = 0; r < 4; ++r) rw[r] = __shfl(rl, lg * 4 + r);
#pragma unroll
  for (int nf = 0; nf < 4; ++nf)
#pragma unroll
    for (int r = 0; r < 4; ++r) {
      float val = o[nf][r] * rw[r];
      out[((size_t)(b * 1024 + tw + lg * 4 + r)) * 1024 + h * 64 + nf * 16 + l15] = f2bf(val);
    }
}

extern "C" void kernel_launch(void* const* d_in, const int* in_sizes, int n_in, void* d_out,
                              int out_size, void* d_ws, size_t ws_size, hipStream_t stream) {
  (void)in_sizes; (void)n_in; (void)out_size; (void)ws_size;
  const float* x = (const float*)d_in[0];
  const float* pos_k = (const float*)d_in[1];
  const int* mask = (const int*)d_in[2];
  const float* ln_scale = (const float*)d_in[3];
  const float* ln_bias = (const float*)d_in[4];
  const float* wq = (const float*)d_in[5];
  const float* bq = (const float*)d_in[6];
  const float* wk = (const float*)d_in[7];
  const float* bk = (const float*)d_in[8];
  const float* wv = (const float*)d_in[9];
  const float* bv = (const float*)d_in[10];
  const float* wo = (const float*)d_in[11];
  const float* bo = (const float*)d_in[12];
  float* out = (float*)d_out;
  char* ws = (char*)d_ws;
  const size_t MB = 1ull << 20;
  ushort_t* xn = (ushort_t*)(ws + 0 * MB);   // 16 MB; region reused for mbits after QKV
  ushort_t* qb = (ushort_t*)(ws + 16 * MB);
  ushort_t* kb = (ushort_t*)(ws + 32 * MB);
  ushort_t* vb = (ushort_t*)(ws + 48 * MB);
  ushort_t* ao = (ushort_t*)(ws + 64 * MB);
  ushort_t* wqb = (ushort_t*)(ws + 80 * MB);
  ushort_t* wkb = (ushort_t*)(ws + 82 * MB);
  ushort_t* wvb = (ushort_t*)(ws + 84 * MB);
  ushort_t* wob = (ushort_t*)(ws + 86 * MB);
  ushort_t* ball = (ushort_t*)(ws + 88 * MB);  // 256 MB -> ws >= 344 MB (verified round 0)
  unsigned* mbits = (unsigned*)(ws + 0 * MB);  // 1 MB, reuses xn region (dead after QKV)

  cvt4_kernel<<<4096, 256, 0, stream>>>(wq, wk, wv, wo, wqb, wkb, wvb, wob);
  ln_kernel<<<8192, 256, 0, stream>>>(x, ln_scale, ln_bias, xn);
  dim3 gg(8, 64);
  gemm_bt<0><<<gg, 256, 0, stream>>>(xn, wqb, bq, qb, 8192, 1024, 1024);
  gemm_bt<0><<<gg, 256, 0, stream>>>(xn, wkb, bk, kb, 8192, 1024, 1024);
  gemm_bt<0><<<gg, 256, 0, stream>>>(xn, wvb, bv, vb, 8192, 1024, 1024);
  maskpack_kernel<<<8192, 256, 0, stream>>>(mask, mbits);  // after QKV: xn region now free
  ball_kernel<<<dim3(2, 1024), 256, 0, stream>>>(qb, pos_k, ball);
  attn_kernel<<<dim3(16, 128), 256, 0, stream>>>(qb, kb, vb, ball, mbits, ao);
  gemm_bt<1><<<gg, 256, 0, stream>>>(ao, wob, bo, out, 8192, 1024, 1024);
}